// Round 7
// baseline (329.645 us; speedup 1.0000x reference)
//
#include <hip/hip_runtime.h>

typedef unsigned short u16;
typedef __attribute__((ext_vector_type(8))) short short8;
typedef __attribute__((ext_vector_type(4))) short short4v;
typedef __attribute__((ext_vector_type(4))) float floatx4;

// round-half-up bf16 (1 add + 1 shr); max error 0.5 ulp like RTNE (ties round up)
__device__ __forceinline__ u16 f2bf(float f) {
  return (u16)((__float_as_uint(f) + 0x8000u) >> 16);
}
__device__ __forceinline__ float bf2f(u16 v) {
  return __uint_as_float(((unsigned)v) << 16);
}
// pack two floats -> u32 of 2 bf16 (lo = a, hi = b) in ONE VALU op
__device__ __forceinline__ unsigned cvt_pk_bf16(float a, float b) {
  unsigned r;
  asm("v_cvt_pk_bf16_f32 %0, %1, %2" : "=v"(r) : "v"(a), "v"(b));
  return r;
}

#define GLD16(g, l) __builtin_amdgcn_global_load_lds( \
    (const __attribute__((address_space(1))) void*)(g), \
    (__attribute__((address_space(3))) void*)(l), 16, 0, 0)

// ---------------- prep: 4 weight transposes + rmsnorm(x,y), one launch ----------------
// z<4: transpose fp32(K,N)->bf16(N,K).  z==4: RMSNorm*(1+scale)->bf16 rows.
__global__ __launch_bounds__(256) void prep(const float* __restrict__ W0, u16* __restrict__ T0,
                                            const float* __restrict__ W1, u16* __restrict__ T1,
                                            const float* __restrict__ W2, u16* __restrict__ T2,
                                            const float* __restrict__ W3, u16* __restrict__ T3,
                                            const float* __restrict__ x, const float* __restrict__ scale_x,
                                            const float* __restrict__ y, const float* __restrict__ scale_y,
                                            u16* __restrict__ xm, u16* __restrict__ ym) {
  __shared__ float t[32][33];
  const int z = blockIdx.z;
  if (z < 4) {
    const float* in; u16* out; int K, N;
    switch (z) {
      case 0: in = W0; out = T0; K = 1536; N = 4608; break;
      case 1: in = W1; out = T1; K = 768;  N = 4608; break;
      case 2: in = W2; out = T2; K = 1536; N = 1536; break;
      default: in = W3; out = T3; K = 1536; N = 768; break;
    }
    const int n0 = blockIdx.x * 32, k0 = blockIdx.y * 32;
    if (n0 >= N || k0 >= K) return;
    const int tx = threadIdx.x, ty = threadIdx.y;   // 32 x 8
#pragma unroll
    for (int i = 0; i < 32; i += 8)
      t[ty + i][tx] = in[(size_t)(k0 + ty + i) * N + n0 + tx];
    __syncthreads();
#pragma unroll
    for (int i = 0; i < 32; i += 8)
      out[(size_t)(n0 + ty + i) * K + k0 + tx] = f2bf(t[tx][ty + i]);
  } else {
    const int row = blockIdx.y * 144 + blockIdx.x;
    if (row >= 2304) return;
    const int tid = threadIdx.y * 32 + threadIdx.x;
    const float* xr; const float* sc; u16* dst; int D;
    if (row < 2048) { D = 1536; xr = x + (size_t)row * D; sc = scale_x; dst = xm + (size_t)row * D; }
    else { D = 768; xr = y + (size_t)(row - 2048) * D; sc = scale_y; dst = ym + (size_t)(row - 2048) * D; }
    float ss = 0.f;
    for (int c = tid; c < D; c += 256) { float v = xr[c]; ss += v * v; }
    for (int off = 32; off > 0; off >>= 1) ss += __shfl_down(ss, off);
    __shared__ float red[4];
    if ((tid & 63) == 0) red[tid >> 6] = ss;
    __syncthreads();
    const float tot = red[0] + red[1] + red[2] + red[3];
    const float r = rsqrtf(tot / (float)D + 1e-6f);
    for (int c = tid; c < D; c += 256)
      dst[c] = f2bf(xr[c] * r * (1.0f + sc[c]));
  }
}

// ---------------- dual bf16 MFMA GEMM, 3-stage counted-vmcnt K-pipeline ----------
// C(MxN) = A(MxK) * BT(NxK)^T + bias. M%128==0, N%128==0, K%32==0.
// 3 buffers: tile t+2 issued each iter, vmcnt(8) leaves t+1/t+2 in flight -> each
// load gets ~2 iterations (~800cy) of latency cover vs ~400cy with 2-stage (R5).
// Grid-limited (<=2.5 blocks/CU), so 48KB LDS costs no residency.
template <bool BOUT>
__global__ __launch_bounds__(256) void gemm2(const u16* __restrict__ A0, const u16* __restrict__ BT0,
                                             const float* __restrict__ bias0, void* __restrict__ C0,
                                             int M0, int N0, int K0,
                                             const u16* __restrict__ A1, const u16* __restrict__ BT1,
                                             const float* __restrict__ bias1, void* __restrict__ C1,
                                             int M1, int N1, int K1) {
  const u16 *A, *BT; const float* bias; void* Cout; int M, N, K;
  if (blockIdx.z == 0) { A = A0; BT = BT0; bias = bias0; Cout = C0; M = M0; N = N0; K = K0; }
  else { A = A1; BT = BT1; bias = bias1; Cout = C1; M = M1; N = N1; K = K1; }
  const int bm = blockIdx.y * 128, bn = blockIdx.x * 128;
  if (bm >= M || bn >= N) return;

  __shared__ __align__(16) u16 As[3][128 * 32];
  __shared__ __align__(16) u16 Bs[3][128 * 32];
  const int tid = threadIdx.x;
  const int lane = tid & 63, wave = tid >> 6;
  const int wm = (wave & 1) * 64, wn = (wave >> 1) * 64;
  const int row16 = lane & 15, quad = lane >> 4;

  floatx4 acc[4][4] = {};
  const int r0 = lane >> 2, c4 = (lane & 3) * 8;
  const u16* Ag0 = A + (size_t)(bm + wave * 16 + r0) * K + c4;
  const u16* Ag1 = A + (size_t)(bm + (wave + 4) * 16 + r0) * K + c4;
  const u16* Bg0 = BT + (size_t)(bn + wave * 16 + r0) * K + c4;
  const u16* Bg1 = BT + (size_t)(bn + (wave + 4) * 16 + r0) * K + c4;
  const int d0 = wave * 512, d1 = (wave + 4) * 512;

  // prologue: stage tiles 0 and 1 (K >= 768 always here)
  GLD16(Ag0, &As[0][d0]);
  GLD16(Ag1, &As[0][d1]);
  GLD16(Bg0, &Bs[0][d0]);
  GLD16(Bg1, &Bs[0][d1]);
  GLD16(Ag0 + 32, &As[1][d0]);
  GLD16(Ag1 + 32, &As[1][d1]);
  GLD16(Bg0 + 32, &Bs[1][d0]);
  GLD16(Bg1 + 32, &Bs[1][d1]);

  int cur = 0;
  for (int k0 = 0; k0 < K; k0 += 32) {
    if (k0 + 64 < K) {
      int nxt2 = cur + 2; if (nxt2 >= 3) nxt2 -= 3;
      GLD16(Ag0 + k0 + 64, &As[nxt2][d0]);
      GLD16(Ag1 + k0 + 64, &As[nxt2][d1]);
      GLD16(Bg0 + k0 + 64, &Bs[nxt2][d0]);
      GLD16(Bg1 + k0 + 64, &Bs[nxt2][d1]);
      asm volatile("s_waitcnt vmcnt(8)" ::: "memory");  // tile t done; t+1,t+2 in flight
    } else if (k0 + 32 < K) {
      asm volatile("s_waitcnt vmcnt(4)" ::: "memory");  // tile t done; t+1 in flight
    } else {
      asm volatile("s_waitcnt vmcnt(0)" ::: "memory");  // last tile: drain
    }
    __builtin_amdgcn_s_barrier();
    asm volatile("" ::: "memory");
    short8 af[4], bf[4];
#pragma unroll
    for (int i = 0; i < 4; i++) {
      af[i] = *(const short8*)&As[cur][(wm + i * 16 + row16) * 32 + quad * 8];
      bf[i] = *(const short8*)&Bs[cur][(wn + i * 16 + row16) * 32 + quad * 8];
    }
#pragma unroll
    for (int mi = 0; mi < 4; mi++)
#pragma unroll
      for (int ni = 0; ni < 4; ni++)
        acc[mi][ni] = __builtin_amdgcn_mfma_f32_16x16x32_bf16(af[mi], bf[ni], acc[mi][ni], 0, 0, 0);
    asm volatile("" ::: "memory");
    __builtin_amdgcn_s_barrier();   // all waves done reading buf[cur]; next iter may overwrite it
    cur += 1; if (cur >= 3) cur -= 3;
  }
#pragma unroll
  for (int mi = 0; mi < 4; mi++) {
#pragma unroll
    for (int ni = 0; ni < 4; ni++) {
      const int col = bn + wn + ni * 16 + row16;
      const float b = bias[col];
      const int row0 = bm + wm + mi * 16 + quad * 4;
#pragma unroll
      for (int r = 0; r < 4; r++) {
        const float v = acc[mi][ni][r] + b;
        if constexpr (BOUT)
          ((u16*)Cout)[(size_t)(row0 + r) * N + col] = f2bf(v);
        else
          ((float*)Cout)[(size_t)(row0 + r) * N + col] = v;
      }
    }
  }
}

// ---------------- per-head q/k RMSNorm + RoPE(x only) + V transpose fused ----------------
// Block = 32 seq x 1 head, 256 threads. RoPE pairs in-lane; V LDS-transposed to Vt (h,d,s).
// Q folded with (1/sqrt(D)) * log2(e) so attention works in exp2 domain.
__global__ __launch_bounds__(256) void qkv_post(const u16* __restrict__ qkvx,
                                                const u16* __restrict__ qkvy,
                                                const float* __restrict__ qnwx, const float* __restrict__ knwx,
                                                const float* __restrict__ qnwy, const float* __restrict__ knwy,
                                                const float* __restrict__ rcos, const float* __restrict__ rsin,
                                                u16* __restrict__ Q, u16* __restrict__ Kb, u16* __restrict__ Vt) {
  const int s0 = blockIdx.x * 32, h = blockIdx.y;
  const int tid = threadIdx.x, wave = tid >> 6, lane = tid & 63;
  const int sl = wave * 8 + (lane >> 3);     // local seq 0..31
  const int s = s0 + sl;
  const int d0 = (lane & 7) * 16;
  const bool isx = s < 2048;
  const u16* base = isx ? (qkvx + (size_t)s * 4608) : (qkvy + (size_t)(s - 2048) * 4608);

  const short8 qv0 = *(const short8*)(base + h * 128 + d0);
  const short8 qv1 = *(const short8*)(base + h * 128 + d0 + 8);
  const short8 kv0 = *(const short8*)(base + 1536 + h * 128 + d0);
  const short8 kv1 = *(const short8*)(base + 1536 + h * 128 + d0 + 8);
  const short8 vv0 = *(const short8*)(base + 3072 + h * 128 + d0);
  const short8 vv1 = *(const short8*)(base + 3072 + h * 128 + d0 + 8);

  float q[16], k[16];
#pragma unroll
  for (int j = 0; j < 8; j++) {
    q[j] = bf2f((u16)qv0[j]); q[j + 8] = bf2f((u16)qv1[j]);
    k[j] = bf2f((u16)kv0[j]); k[j + 8] = bf2f((u16)kv1[j]);
  }
  float sq = 0.f, sk = 0.f;
#pragma unroll
  for (int j = 0; j < 16; j++) { sq += q[j] * q[j]; sk += k[j] * k[j]; }
#pragma unroll
  for (int off = 1; off <= 4; off <<= 1) { sq += __shfl_xor(sq, off); sk += __shfl_xor(sk, off); }
  const float rq = rsqrtf(sq * (1.f / 128.f) + 1e-5f);
  const float rk = rsqrtf(sk * (1.f / 128.f) + 1e-5f);

  const float* qw = isx ? qnwx : qnwy;
  const float* kw = isx ? knwx : knwy;
#pragma unroll
  for (int j = 0; j < 16; j++) {
    q[j] = q[j] * rq * qw[d0 + j];
    k[j] = k[j] * rk * kw[d0 + j];
  }
  if (isx) {
    const float* cb = rcos + ((size_t)s * 12 + h) * 64 + (d0 >> 1);
    const float* sb = rsin + ((size_t)s * 12 + h) * 64 + (d0 >> 1);
#pragma unroll
    for (int p = 0; p < 8; p++) {
      const float c = cb[p], sn = sb[p];
      const float qe = q[2 * p], qo = q[2 * p + 1];
      const float ke = k[2 * p], ko = k[2 * p + 1];
      q[2 * p] = qe * c - qo * sn; q[2 * p + 1] = qe * sn + qo * c;
      k[2 * p] = ke * c - ko * sn; k[2 * p + 1] = ke * sn + ko * c;
    }
  }
  u16 qo16[16], ko16[16];
#pragma unroll
  for (int j = 0; j < 16; j++) {
    qo16[j] = f2bf(q[j] * 0.12751737942f);  // (1/sqrt(128)) * log2(e)
    ko16[j] = f2bf(k[j]);
  }
  const size_t o = ((size_t)h * 2304 + s) * 128 + d0;
  *(short8*)(Q + o) = *(const short8*)&qo16[0];
  *(short8*)(Q + o + 8) = *(const short8*)&qo16[8];
  *(short8*)(Kb + o) = *(const short8*)&ko16[0];
  *(short8*)(Kb + o + 8) = *(const short8*)&ko16[8];

  // V transpose: (32 s x 128 d) block -> Vt (h, d, s)
  __shared__ u16 vlds[128][33];
#pragma unroll
  for (int j = 0; j < 8; j++) {
    vlds[d0 + j][sl] = (u16)vv0[j];
    vlds[d0 + 8 + j][sl] = (u16)vv1[j];
  }
  __syncthreads();
  const int row = tid >> 1, sc = (tid & 1) * 16;
  u16 tmp[16];
#pragma unroll
  for (int j = 0; j < 16; j++) tmp[j] = vlds[row][sc + j];
  u16* vdst = Vt + ((size_t)h * 128 + row) * 2304 + s0 + sc;
  *(short8*)vdst = *(const short8*)&tmp[0];
  *(short8*)(vdst + 8) = *(const short8*)&tmp[8];
}

// ---------------- flash attention: 32 q/wave, 128 q/block, 3-way split-K, V from L2 -------
// V staging dropped (m169 pattern): per-XCD V working set ~1MB << 4MB L2, so V-fragments
// load directly from Vt global (same values/order as the staged path -> bitwise-identical).
// Removes 4 GLD16/wave/tile + 40% of LDS read traffic; LDS 48->32KB. vf loads depend only
// on kt so the compiler hoists them over QK+softmax (free T14 overlap).
__global__ __launch_bounds__(256, 3) void attn(const u16* __restrict__ Q, const u16* __restrict__ Kb,
                                               const u16* __restrict__ Vt,
                                               u16* __restrict__ Opart,
                                               float* __restrict__ Mp, float* __restrict__ Lp) {
  const int bid = blockIdx.x;
  const int xcd = bid & 7, local = bid >> 3;     // 0..89
  const int slot = local / 18, qt = local % 18;
  const int combo = slot * 8 + xcd;              // 0..39
  if (combo >= 36) return;                       // 72 pad blocks exit
  const int h = combo % 12, split = combo / 12;  // split 0..2
  const int q0 = qt * 128;
  const int tid = threadIdx.x, lane = tid & 63, wave = tid >> 6;
  const int row16 = lane & 15, quad = lane >> 4;
  const u16* Qh = Q + (size_t)h * 2304 * 128;
  const u16* Kh = Kb + (size_t)h * 2304 * 128;
  const u16* Vh = Vt + (size_t)h * 128 * 2304;

  __shared__ __align__(16) u16 Ks[64 * 128];    // swizzled: 64 key-rows x 16 chunks (16KB)
  __shared__ __align__(16) u16 Ps[4][32 * 64];  // per-wave P (32 q x 64 keys), swizzled (16KB)

  short8 qf[2][4];
#pragma unroll
  for (int g = 0; g < 2; g++) {
    const u16* qrow = Qh + (size_t)(q0 + wave * 32 + g * 16 + row16) * 128;
#pragma unroll
    for (int kk = 0; kk < 4; kk++) qf[g][kk] = *(const short8*)(qrow + kk * 32 + quad * 8);
  }
  floatx4 oacc[2][8] = {};
  float m_i[2] = {-1e30f, -1e30f}, l_i[2] = {0.f, 0.f};

  const u16* Kp[4];
#pragma unroll
  for (int i = 0; i < 4; i++) {
    const int j = i * 4 + wave;
    const int krow = j * 4 + (lane >> 4);        // key row 0..63
    const int kcol = ((lane & 15) ^ (krow & 7)) * 8;
    Kp[i] = Kh + (size_t)krow * 128 + kcol;
  }
  // per-lane V base: row = d (row16 within 16-row group), col chunk = quad
  const u16* vb = Vh + (size_t)row16 * 2304 + quad * 8;
  const int sw = row16 & 7;
  const int kbeg = split * 768, kend = kbeg + 768;

  for (int kt = kbeg; kt < kend; kt += 64) {
    __syncthreads();
#pragma unroll
    for (int i = 0; i < 4; i++)
      GLD16(Kp[i] + (size_t)kt * 128, Ks + (i * 4 + wave) * 512);
    __syncthreads();

    // S^T for both q-halves; K fragment loaded once, used twice
    floatx4 sacc[2][4] = {};
#pragma unroll
    for (int mk = 0; mk < 4; mk++) {
#pragma unroll
      for (int kk = 0; kk < 4; kk++) {
        const int c = (4 * kk + quad) ^ sw;
        const short8 kfrag = *(const short8*)&Ks[(mk * 16 + row16) * 128 + c * 8];
        sacc[0][mk] = __builtin_amdgcn_mfma_f32_16x16x32_bf16(kfrag, qf[0][kk], sacc[0][mk], 0, 0, 0);
        sacc[1][mk] = __builtin_amdgcn_mfma_f32_16x16x32_bf16(kfrag, qf[1][kk], sacc[1][mk], 0, 0, 0);
      }
    }
    // online softmax per q-half: keys in-lane, q-col = row16
#pragma unroll
    for (int g = 0; g < 2; g++) {
      float mx = sacc[g][0][0];
#pragma unroll
      for (int mk = 0; mk < 4; mk++)
#pragma unroll
        for (int r = 0; r < 4; r++) mx = fmaxf(mx, sacc[g][mk][r]);
      mx = fmaxf(mx, __shfl_xor(mx, 16));
      mx = fmaxf(mx, __shfl_xor(mx, 32));
      if (__any(mx > m_i[g] + 8.f)) {  // defer-max: only rescale on >2^8 growth
        const float mnew = fmaxf(m_i[g], mx);
        const float alpha = __builtin_amdgcn_exp2f(m_i[g] - mnew);
        m_i[g] = mnew;
        const float a0 = __shfl(alpha, quad * 4 + 0);
        const float a1 = __shfl(alpha, quad * 4 + 1);
        const float a2 = __shfl(alpha, quad * 4 + 2);
        const float a3 = __shfl(alpha, quad * 4 + 3);
#pragma unroll
        for (int nd = 0; nd < 8; nd++) {
          oacc[g][nd][0] *= a0; oacc[g][nd][1] *= a1; oacc[g][nd][2] *= a2; oacc[g][nd][3] *= a3;
        }
        l_i[g] *= alpha;
      }
      float s = 0.f;
#pragma unroll
      for (int mk = 0; mk < 4; mk++)
#pragma unroll
        for (int r = 0; r < 4; r++) {
          const float p = __builtin_amdgcn_exp2f(sacc[g][mk][r] - m_i[g]);
          sacc[g][mk][r] = p;
          s += p;
        }
      s += __shfl_xor(s, 16);
      s += __shfl_xor(s, 32);
      l_i[g] += s;
    }

    // P -> per-wave swizzled LDS via v_cvt_pk_bf16_f32 (1 op per 2 vals)
#pragma unroll
    for (int g = 0; g < 2; g++)
#pragma unroll
      for (int mk = 0; mk < 4; mk++) {
        const int subp = (4 * mk + quad) ^ (sw << 1);
        uint2 pk;
        pk.x = cvt_pk_bf16(sacc[g][mk][0], sacc[g][mk][1]);
        pk.y = cvt_pk_bf16(sacc[g][mk][2], sacc[g][mk][3]);
        *(uint2*)&Ps[wave][(g * 16 + row16) * 64 + subp * 4] = pk;
      }
    const int pc0 = quad ^ sw, pc1 = (4 + quad) ^ sw;
    short8 pf[2][2];
#pragma unroll
    for (int g = 0; g < 2; g++) {
      pf[g][0] = *(const short8*)&Ps[wave][(g * 16 + row16) * 64 + pc0 * 8];
      pf[g][1] = *(const short8*)&Ps[wave][(g * 16 + row16) * 64 + pc1 * 8];
    }
    // PV: V fragments direct from L2 (identical values to the old staged+swizzled read)
    const u16* vkt = vb + kt;
#pragma unroll
    for (int nd = 0; nd < 8; nd++) {
      const short8 vf0 = *(const short8*)(vkt + (size_t)(nd * 16) * 2304);
      const short8 vf1 = *(const short8*)(vkt + (size_t)(nd * 16) * 2304 + 32);
      oacc[0][nd] = __builtin_amdgcn_mfma_f32_16x16x32_bf16(pf[0][0], vf0, oacc[0][nd], 0, 0, 0);
      oacc[0][nd] = __builtin_amdgcn_mfma_f32_16x16x32_bf16(pf[0][1], vf1, oacc[0][nd], 0, 0, 0);
      oacc[1][nd] = __builtin_amdgcn_mfma_f32_16x16x32_bf16(pf[1][0], vf0, oacc[1][nd], 0, 0, 0);
      oacc[1][nd] = __builtin_amdgcn_mfma_f32_16x16x32_bf16(pf[1][1], vf1, oacc[1][nd], 0, 0, 0);
    }
  }
#pragma unroll
  for (int g = 0; g < 2; g++) {
    const size_t base = (size_t)(split * 12 + h) * 2304 + q0 + wave * 32 + g * 16;
#pragma unroll
    for (int nd = 0; nd < 8; nd++)
#pragma unroll
      for (int r = 0; r < 4; r++)
        Opart[(base + quad * 4 + r) * 128 + nd * 16 + row16] = f2bf(oacc[g][nd][r]);
    if (lane < 16) { Mp[base + lane] = m_i[g]; Lp[base + lane] = l_i[g]; }
  }
}

// ---------------- combine 3 splits (bf16 partials) -> attnout bf16 (S, 1536) ----------------
__global__ __launch_bounds__(256) void attn_combine(const u16* __restrict__ Opart,
                                                    const float* __restrict__ Mp,
                                                    const float* __restrict__ Lp,
                                                    u16* __restrict__ attnout) {
  const int idx = blockIdx.x * 256 + threadIdx.x;   // one per 4 output elems
  const int dd = (idx & 31) * 4;
  const int hq = idx >> 5;
  const int h = hq % 12, q = hq / 12;
  size_t b[3]; float ms[3], ls[3];
  float m = -1e30f;
#pragma unroll
  for (int s = 0; s < 3; s++) {
    b[s] = (size_t)(s * 12 + h) * 2304 + q;
    ms[s] = Mp[b[s]]; ls[s] = Lp[b[s]];
    m = fmaxf(m, ms[s]);
  }
  float w[3], denom = 0.f;
#pragma unroll
  for (int s = 0; s < 3; s++) { w[s] = exp2f(ms[s] - m); denom += ls[s] * w[s]; }
  const float inv = 1.0f / denom;
  float ox = 0.f, oy = 0.f, oz = 0.f, ow = 0.f;
#pragma unroll
  for (int s = 0; s < 3; s++) {
    const short4v o = *(const short4v*)&Opart[b[s] * 128 + dd];
    ox += bf2f((u16)o[0]) * w[s]; oy += bf2f((u16)o[1]) * w[s];
    oz += bf2f((u16)o[2]) * w[s]; ow += bf2f((u16)o[3]) * w[s];
  }
  short4v out;
  out[0] = (short)f2bf(ox * inv);
  out[1] = (short)f2bf(oy * inv);
  out[2] = (short)f2bf(oz * inv);
  out[3] = (short)f2bf(ow * inv);
  *(short4v*)&attnout[(size_t)idx * 4] = out;
}

// ---------------- launch ----------------
extern "C" void kernel_launch(void* const* d_in, const int* in_sizes, int n_in,
                              void* d_out, int out_size, void* d_ws, size_t ws_size,
                              hipStream_t stream) {
  const float* x        = (const float*)d_in[0];
  const float* y        = (const float*)d_in[1];
  const float* scale_x  = (const float*)d_in[2];
  const float* scale_y  = (const float*)d_in[3];
  const float* rope_cos = (const float*)d_in[4];
  const float* rope_sin = (const float*)d_in[5];
  const float* Wqkv_x   = (const float*)d_in[6];
  const float* bqkv_x   = (const float*)d_in[7];
  const float* Wqkv_y   = (const float*)d_in[8];
  const float* bqkv_y   = (const float*)d_in[9];
  const float* qnwx     = (const float*)d_in[10];
  const float* knwx     = (const float*)d_in[11];
  const float* qnwy     = (const float*)d_in[12];
  const float* knwy     = (const float*)d_in[13];
  const float* Wproj_x  = (const float*)d_in[14];
  const float* bproj_x  = (const float*)d_in[15];
  const float* Wproj_y  = (const float*)d_in[16];
  const float* bproj_y  = (const float*)d_in[17];
  float* out = (float*)d_out;

  char* ws = (char*)d_ws;
  size_t off = 0;
  auto take = [&](size_t bytes) { char* p = ws + off; off += (bytes + 255) & ~(size_t)255; return p; };
  u16* WqkvxT  = (u16*)take((size_t)4608 * 1536 * 2);
  u16* WqkvyT  = (u16*)take((size_t)4608 * 768 * 2);
  u16* WprojxT = (u16*)take((size_t)1536 * 1536 * 2);
  u16* WprojyT = (u16*)take((size_t)768 * 1536 * 2);
  u16* xm      = (u16*)take((size_t)2048 * 1536 * 2);
  u16* ym      = (u16*)take((size_t)256 * 768 * 2);
  u16* qkvx    = (u16*)take((size_t)2048 * 4608 * 2);
  u16* qkvy    = (u16*)take((size_t)256 * 4608 * 2);
  u16* Qb      = (u16*)take((size_t)12 * 2304 * 128 * 2);
  u16* Kb      = (u16*)take((size_t)12 * 2304 * 128 * 2);
  u16* Vt      = (u16*)take((size_t)12 * 128 * 2304 * 2);
  u16* attnout = (u16*)take((size_t)2304 * 1536 * 2);
  u16* Opart   = (u16*)take((size_t)3 * 12 * 2304 * 128 * 2);
  float* Mp    = (float*)take((size_t)3 * 12 * 2304 * 4);
  float* Lp    = (float*)take((size_t)3 * 12 * 2304 * 4);

  prep<<<dim3(144, 48, 5), dim3(32, 8), 0, stream>>>(Wqkv_x, WqkvxT, Wqkv_y, WqkvyT,
                                                     Wproj_x, WprojxT, Wproj_y, WprojyT,
                                                     x, scale_x, y, scale_y, xm, ym);

  gemm2<true><<<dim3(36, 16, 2), 256, 0, stream>>>(xm, WqkvxT, bqkv_x, qkvx, 2048, 4608, 1536,
                                                   ym, WqkvyT, bqkv_y, qkvy, 256, 4608, 768);

  qkv_post<<<dim3(72, 12), 256, 0, stream>>>(qkvx, qkvy, qnwx, knwx, qnwy, knwy,
                                             rope_cos, rope_sin, Qb, Kb, Vt);

  attn<<<dim3(720), 256, 0, stream>>>(Qb, Kb, Vt, Opart, Mp, Lp);
  attn_combine<<<(2304 * 1536 / 4) / 256, 256, 0, stream>>>(Opart, Mp, Lp, attnout);

  gemm2<false><<<dim3(12, 16, 2), 256, 0, stream>>>(attnout, WprojxT, bproj_x, out, 2048, 1536, 1536,
                                                    attnout + (size_t)2048 * 1536, WprojyT, bproj_y,
                                                    out + (size_t)2048 * 1536, 256, 768, 1536);
  (void)in_sizes; (void)n_in; (void)out_size; (void)ws_size;
}

// Round 8
// 298.620 us; speedup vs baseline: 1.1039x; 1.1039x over previous
//
#include <hip/hip_runtime.h>

typedef unsigned short u16;
typedef __attribute__((ext_vector_type(8))) short short8;
typedef __attribute__((ext_vector_type(4))) short short4v;
typedef __attribute__((ext_vector_type(4))) float floatx4;

// round-half-up bf16 (1 add + 1 shr); max error 0.5 ulp like RTNE (ties round up)
__device__ __forceinline__ u16 f2bf(float f) {
  return (u16)((__float_as_uint(f) + 0x8000u) >> 16);
}
__device__ __forceinline__ float bf2f(u16 v) {
  return __uint_as_float(((unsigned)v) << 16);
}
// pack two floats -> u32 of 2 bf16 (lo = a, hi = b) in ONE VALU op
__device__ __forceinline__ unsigned cvt_pk_bf16(float a, float b) {
  unsigned r;
  asm("v_cvt_pk_bf16_f32 %0, %1, %2" : "=v"(r) : "v"(a), "v"(b));
  return r;
}

#define GLD16(g, l) __builtin_amdgcn_global_load_lds( \
    (const __attribute__((address_space(1))) void*)(g), \
    (__attribute__((address_space(3))) void*)(l), 16, 0, 0)

// ---------------- prep: 4 weight transposes + rmsnorm(x,y), one launch ----------------
// z<4: transpose fp32(K,N)->bf16(N,K).  z==4: RMSNorm*(1+scale)->bf16 rows.
__global__ __launch_bounds__(256) void prep(const float* __restrict__ W0, u16* __restrict__ T0,
                                            const float* __restrict__ W1, u16* __restrict__ T1,
                                            const float* __restrict__ W2, u16* __restrict__ T2,
                                            const float* __restrict__ W3, u16* __restrict__ T3,
                                            const float* __restrict__ x, const float* __restrict__ scale_x,
                                            const float* __restrict__ y, const float* __restrict__ scale_y,
                                            u16* __restrict__ xm, u16* __restrict__ ym) {
  __shared__ float t[32][33];
  const int z = blockIdx.z;
  if (z < 4) {
    const float* in; u16* out; int K, N;
    switch (z) {
      case 0: in = W0; out = T0; K = 1536; N = 4608; break;
      case 1: in = W1; out = T1; K = 768;  N = 4608; break;
      case 2: in = W2; out = T2; K = 1536; N = 1536; break;
      default: in = W3; out = T3; K = 1536; N = 768; break;
    }
    const int n0 = blockIdx.x * 32, k0 = blockIdx.y * 32;
    if (n0 >= N || k0 >= K) return;
    const int tx = threadIdx.x, ty = threadIdx.y;   // 32 x 8
#pragma unroll
    for (int i = 0; i < 32; i += 8)
      t[ty + i][tx] = in[(size_t)(k0 + ty + i) * N + n0 + tx];
    __syncthreads();
#pragma unroll
    for (int i = 0; i < 32; i += 8)
      out[(size_t)(n0 + ty + i) * K + k0 + tx] = f2bf(t[tx][ty + i]);
  } else {
    const int row = blockIdx.y * 144 + blockIdx.x;
    if (row >= 2304) return;
    const int tid = threadIdx.y * 32 + threadIdx.x;
    const float* xr; const float* sc; u16* dst; int D;
    if (row < 2048) { D = 1536; xr = x + (size_t)row * D; sc = scale_x; dst = xm + (size_t)row * D; }
    else { D = 768; xr = y + (size_t)(row - 2048) * D; sc = scale_y; dst = ym + (size_t)(row - 2048) * D; }
    float ss = 0.f;
    for (int c = tid; c < D; c += 256) { float v = xr[c]; ss += v * v; }
    for (int off = 32; off > 0; off >>= 1) ss += __shfl_down(ss, off);
    __shared__ float red[4];
    if ((tid & 63) == 0) red[tid >> 6] = ss;
    __syncthreads();
    const float tot = red[0] + red[1] + red[2] + red[3];
    const float r = rsqrtf(tot / (float)D + 1e-6f);
    for (int c = tid; c < D; c += 256)
      dst[c] = f2bf(xr[c] * r * (1.0f + sc[c]));
  }
}

// ---------------- dual bf16 MFMA GEMM, 3-stage counted-vmcnt pipe + XCD n-stripe swizzle ----
// C(MxN) = A(MxK) * BT(NxK)^T + bias. M%128==0, N%128==0, K%32==0.
// 1D grid; bijective XCD decode (bid&7 = XCD under round-robin dispatch): each XCD owns a
// contiguous n-stripe (B-stripe ~1.8MB stays L2-resident) and streams full A (6.3MB shared
// by its co-resident blocks). Per-XCD L2 footprint ~8MB vs ~20MB with linear dispatch ->
// cuts A/B panel re-fetch from HBM (the qkv-gemm's dominant cost by arithmetic).
template <bool BOUT>
__global__ __launch_bounds__(256) void gemm2(const u16* __restrict__ A0, const u16* __restrict__ BT0,
                                             const float* __restrict__ bias0, void* __restrict__ C0,
                                             int M0, int N0, int K0,
                                             const u16* __restrict__ A1, const u16* __restrict__ BT1,
                                             const float* __restrict__ bias1, void* __restrict__ C1,
                                             int M1, int N1, int K1) {
  const u16 *A, *BT; const float* bias; void* Cout; int M, N, K;
  if (blockIdx.z == 0) { A = A0; BT = BT0; bias = bias0; Cout = C0; M = M0; N = N0; K = K0; }
  else { A = A1; BT = BT1; bias = bias1; Cout = C1; M = M1; N = N1; K = K1; }
  const int nty = M >> 7, ntx = N >> 7;
  const int W = ntx * nty;
  const int bid = blockIdx.x;
  const int xcd = bid & 7, local = bid >> 3;
  const int q = W >> 3, r = W & 7;
  const int cap = (xcd < r) ? q + 1 : q;
  if (local >= cap) return;
  const int w = (xcd < r) ? xcd * (q + 1) + local
                          : r * (q + 1) + (xcd - r) * q + local;
  const int tx = w / nty, ty = w - tx * nty;   // n-major: XCD's n-stripe, m-sweep inner
  const int bm = ty * 128, bn = tx * 128;

  __shared__ __align__(16) u16 As[3][128 * 32];
  __shared__ __align__(16) u16 Bs[3][128 * 32];
  const int tid = threadIdx.x;
  const int lane = tid & 63, wave = tid >> 6;
  const int wm = (wave & 1) * 64, wn = (wave >> 1) * 64;
  const int row16 = lane & 15, quad = lane >> 4;

  floatx4 acc[4][4] = {};
  const int r0 = lane >> 2, c4 = (lane & 3) * 8;
  const u16* Ag0 = A + (size_t)(bm + wave * 16 + r0) * K + c4;
  const u16* Ag1 = A + (size_t)(bm + (wave + 4) * 16 + r0) * K + c4;
  const u16* Bg0 = BT + (size_t)(bn + wave * 16 + r0) * K + c4;
  const u16* Bg1 = BT + (size_t)(bn + (wave + 4) * 16 + r0) * K + c4;
  const int d0 = wave * 512, d1 = (wave + 4) * 512;

  // prologue: stage tiles 0 and 1 (K >= 768 always here)
  GLD16(Ag0, &As[0][d0]);
  GLD16(Ag1, &As[0][d1]);
  GLD16(Bg0, &Bs[0][d0]);
  GLD16(Bg1, &Bs[0][d1]);
  GLD16(Ag0 + 32, &As[1][d0]);
  GLD16(Ag1 + 32, &As[1][d1]);
  GLD16(Bg0 + 32, &Bs[1][d0]);
  GLD16(Bg1 + 32, &Bs[1][d1]);

  int cur = 0;
  for (int k0 = 0; k0 < K; k0 += 32) {
    if (k0 + 64 < K) {
      int nxt2 = cur + 2; if (nxt2 >= 3) nxt2 -= 3;
      GLD16(Ag0 + k0 + 64, &As[nxt2][d0]);
      GLD16(Ag1 + k0 + 64, &As[nxt2][d1]);
      GLD16(Bg0 + k0 + 64, &Bs[nxt2][d0]);
      GLD16(Bg1 + k0 + 64, &Bs[nxt2][d1]);
      asm volatile("s_waitcnt vmcnt(8)" ::: "memory");  // tile t done; t+1,t+2 in flight
    } else if (k0 + 32 < K) {
      asm volatile("s_waitcnt vmcnt(4)" ::: "memory");  // tile t done; t+1 in flight
    } else {
      asm volatile("s_waitcnt vmcnt(0)" ::: "memory");  // last tile: drain
    }
    __builtin_amdgcn_s_barrier();
    asm volatile("" ::: "memory");
    short8 af[4], bf[4];
#pragma unroll
    for (int i = 0; i < 4; i++) {
      af[i] = *(const short8*)&As[cur][(wm + i * 16 + row16) * 32 + quad * 8];
      bf[i] = *(const short8*)&Bs[cur][(wn + i * 16 + row16) * 32 + quad * 8];
    }
#pragma unroll
    for (int mi = 0; mi < 4; mi++)
#pragma unroll
      for (int ni = 0; ni < 4; ni++)
        acc[mi][ni] = __builtin_amdgcn_mfma_f32_16x16x32_bf16(af[mi], bf[ni], acc[mi][ni], 0, 0, 0);
    asm volatile("" ::: "memory");
    __builtin_amdgcn_s_barrier();   // all waves done reading buf[cur]; next iter may overwrite it
    cur += 1; if (cur >= 3) cur -= 3;
  }
#pragma unroll
  for (int mi = 0; mi < 4; mi++) {
#pragma unroll
    for (int ni = 0; ni < 4; ni++) {
      const int col = bn + wn + ni * 16 + row16;
      const float b = bias[col];
      const int row0 = bm + wm + mi * 16 + quad * 4;
#pragma unroll
      for (int r2 = 0; r2 < 4; r2++) {
        const float v = acc[mi][ni][r2] + b;
        if constexpr (BOUT)
          ((u16*)Cout)[(size_t)(row0 + r2) * N + col] = f2bf(v);
        else
          ((float*)Cout)[(size_t)(row0 + r2) * N + col] = v;
      }
    }
  }
}

// ---------------- per-head q/k RMSNorm + RoPE(x only) + V transpose fused ----------------
// Block = 32 seq x 1 head, 256 threads. RoPE pairs in-lane; V LDS-transposed to Vt (h,d,s).
// Q folded with (1/sqrt(D)) * log2(e) so attention works in exp2 domain.
__global__ __launch_bounds__(256) void qkv_post(const u16* __restrict__ qkvx,
                                                const u16* __restrict__ qkvy,
                                                const float* __restrict__ qnwx, const float* __restrict__ knwx,
                                                const float* __restrict__ qnwy, const float* __restrict__ knwy,
                                                const float* __restrict__ rcos, const float* __restrict__ rsin,
                                                u16* __restrict__ Q, u16* __restrict__ Kb, u16* __restrict__ Vt) {
  const int s0 = blockIdx.x * 32, h = blockIdx.y;
  const int tid = threadIdx.x, wave = tid >> 6, lane = tid & 63;
  const int sl = wave * 8 + (lane >> 3);     // local seq 0..31
  const int s = s0 + sl;
  const int d0 = (lane & 7) * 16;
  const bool isx = s < 2048;
  const u16* base = isx ? (qkvx + (size_t)s * 4608) : (qkvy + (size_t)(s - 2048) * 4608);

  const short8 qv0 = *(const short8*)(base + h * 128 + d0);
  const short8 qv1 = *(const short8*)(base + h * 128 + d0 + 8);
  const short8 kv0 = *(const short8*)(base + 1536 + h * 128 + d0);
  const short8 kv1 = *(const short8*)(base + 1536 + h * 128 + d0 + 8);
  const short8 vv0 = *(const short8*)(base + 3072 + h * 128 + d0);
  const short8 vv1 = *(const short8*)(base + 3072 + h * 128 + d0 + 8);

  float q[16], k[16];
#pragma unroll
  for (int j = 0; j < 8; j++) {
    q[j] = bf2f((u16)qv0[j]); q[j + 8] = bf2f((u16)qv1[j]);
    k[j] = bf2f((u16)kv0[j]); k[j + 8] = bf2f((u16)kv1[j]);
  }
  float sq = 0.f, sk = 0.f;
#pragma unroll
  for (int j = 0; j < 16; j++) { sq += q[j] * q[j]; sk += k[j] * k[j]; }
#pragma unroll
  for (int off = 1; off <= 4; off <<= 1) { sq += __shfl_xor(sq, off); sk += __shfl_xor(sk, off); }
  const float rq = rsqrtf(sq * (1.f / 128.f) + 1e-5f);
  const float rk = rsqrtf(sk * (1.f / 128.f) + 1e-5f);

  const float* qw = isx ? qnwx : qnwy;
  const float* kw = isx ? knwx : knwy;
#pragma unroll
  for (int j = 0; j < 16; j++) {
    q[j] = q[j] * rq * qw[d0 + j];
    k[j] = k[j] * rk * kw[d0 + j];
  }
  if (isx) {
    const float* cb = rcos + ((size_t)s * 12 + h) * 64 + (d0 >> 1);
    const float* sb = rsin + ((size_t)s * 12 + h) * 64 + (d0 >> 1);
#pragma unroll
    for (int p = 0; p < 8; p++) {
      const float c = cb[p], sn = sb[p];
      const float qe = q[2 * p], qo = q[2 * p + 1];
      const float ke = k[2 * p], ko = k[2 * p + 1];
      q[2 * p] = qe * c - qo * sn; q[2 * p + 1] = qe * sn + qo * c;
      k[2 * p] = ke * c - ko * sn; k[2 * p + 1] = ke * sn + ko * c;
    }
  }
  u16 qo16[16], ko16[16];
#pragma unroll
  for (int j = 0; j < 16; j++) {
    qo16[j] = f2bf(q[j] * 0.12751737942f);  // (1/sqrt(128)) * log2(e)
    ko16[j] = f2bf(k[j]);
  }
  const size_t o = ((size_t)h * 2304 + s) * 128 + d0;
  *(short8*)(Q + o) = *(const short8*)&qo16[0];
  *(short8*)(Q + o + 8) = *(const short8*)&qo16[8];
  *(short8*)(Kb + o) = *(const short8*)&ko16[0];
  *(short8*)(Kb + o + 8) = *(const short8*)&ko16[8];

  // V transpose: (32 s x 128 d) block -> Vt (h, d, s)
  __shared__ u16 vlds[128][33];
#pragma unroll
  for (int j = 0; j < 8; j++) {
    vlds[d0 + j][sl] = (u16)vv0[j];
    vlds[d0 + 8 + j][sl] = (u16)vv1[j];
  }
  __syncthreads();
  const int row = tid >> 1, sc = (tid & 1) * 16;
  u16 tmp[16];
#pragma unroll
  for (int j = 0; j < 16; j++) tmp[j] = vlds[row][sc + j];
  u16* vdst = Vt + ((size_t)h * 128 + row) * 2304 + s0 + sc;
  *(short8*)vdst = *(const short8*)&tmp[0];
  *(short8*)(vdst + 8) = *(const short8*)&tmp[8];
}

// ---------------- flash attention: 32 q/wave, 128 q/block, 3-way split-K (R6-exact) -------
// GLD16-staged K AND V (R7 showed direct-L2 V costs +29us: per-wave load latency on the
// PV critical path + 4x V traffic). 48KB LDS, 3 blocks/CU, all 648 working blocks resident.
__global__ __launch_bounds__(256, 3) void attn(const u16* __restrict__ Q, const u16* __restrict__ Kb,
                                               const u16* __restrict__ Vt,
                                               u16* __restrict__ Opart,
                                               float* __restrict__ Mp, float* __restrict__ Lp) {
  const int bid = blockIdx.x;
  const int xcd = bid & 7, local = bid >> 3;     // 0..89
  const int slot = local / 18, qt = local % 18;
  const int combo = slot * 8 + xcd;              // 0..39
  if (combo >= 36) return;                       // 72 pad blocks exit
  const int h = combo % 12, split = combo / 12;  // split 0..2
  const int q0 = qt * 128;
  const int tid = threadIdx.x, lane = tid & 63, wave = tid >> 6;
  const int row16 = lane & 15, quad = lane >> 4;
  const u16* Qh = Q + (size_t)h * 2304 * 128;
  const u16* Kh = Kb + (size_t)h * 2304 * 128;
  const u16* Vh = Vt + (size_t)h * 128 * 2304;

  __shared__ __align__(16) u16 Ks[64 * 128];    // swizzled: 64 key-rows x 16 chunks
  __shared__ __align__(16) u16 Vs[128 * 64];    // swizzled: 128 d-rows x 8 chunks
  __shared__ __align__(16) u16 Ps[4][32 * 64];  // per-wave P (32 q x 64 keys), swizzled

  short8 qf[2][4];
#pragma unroll
  for (int g = 0; g < 2; g++) {
    const u16* qrow = Qh + (size_t)(q0 + wave * 32 + g * 16 + row16) * 128;
#pragma unroll
    for (int kk = 0; kk < 4; kk++) qf[g][kk] = *(const short8*)(qrow + kk * 32 + quad * 8);
  }
  floatx4 oacc[2][8] = {};
  float m_i[2] = {-1e30f, -1e30f}, l_i[2] = {0.f, 0.f};

  const u16* Kp[4]; const u16* Vp[4];
#pragma unroll
  for (int i = 0; i < 4; i++) {
    const int j = i * 4 + wave;
    const int krow = j * 4 + (lane >> 4);        // key row 0..63
    const int kcol = ((lane & 15) ^ (krow & 7)) * 8;
    const int vrow = j * 8 + (lane >> 3);        // d row 0..127
    const int vcol = ((lane & 7) ^ (vrow & 7)) * 8;
    Kp[i] = Kh + (size_t)krow * 128 + kcol;
    Vp[i] = Vh + (size_t)vrow * 2304 + vcol;
  }
  const int sw = row16 & 7;
  const int kbeg = split * 768, kend = kbeg + 768;

  for (int kt = kbeg; kt < kend; kt += 64) {
    __syncthreads();
#pragma unroll
    for (int i = 0; i < 4; i++) {
      GLD16(Kp[i] + (size_t)kt * 128, Ks + (i * 4 + wave) * 512);
      GLD16(Vp[i] + kt, Vs + (i * 4 + wave) * 512);
    }
    __syncthreads();

    // S^T for both q-halves; K fragment loaded once, used twice
    floatx4 sacc[2][4] = {};
#pragma unroll
    for (int mk = 0; mk < 4; mk++) {
#pragma unroll
      for (int kk = 0; kk < 4; kk++) {
        const int c = (4 * kk + quad) ^ sw;
        const short8 kfrag = *(const short8*)&Ks[(mk * 16 + row16) * 128 + c * 8];
        sacc[0][mk] = __builtin_amdgcn_mfma_f32_16x16x32_bf16(kfrag, qf[0][kk], sacc[0][mk], 0, 0, 0);
        sacc[1][mk] = __builtin_amdgcn_mfma_f32_16x16x32_bf16(kfrag, qf[1][kk], sacc[1][mk], 0, 0, 0);
      }
    }
    // online softmax per q-half: keys in-lane, q-col = row16
#pragma unroll
    for (int g = 0; g < 2; g++) {
      float mx = sacc[g][0][0];
#pragma unroll
      for (int mk = 0; mk < 4; mk++)
#pragma unroll
        for (int r = 0; r < 4; r++) mx = fmaxf(mx, sacc[g][mk][r]);
      mx = fmaxf(mx, __shfl_xor(mx, 16));
      mx = fmaxf(mx, __shfl_xor(mx, 32));
      if (__any(mx > m_i[g] + 8.f)) {  // defer-max: only rescale on >2^8 growth
        const float mnew = fmaxf(m_i[g], mx);
        const float alpha = __builtin_amdgcn_exp2f(m_i[g] - mnew);
        m_i[g] = mnew;
        const float a0 = __shfl(alpha, quad * 4 + 0);
        const float a1 = __shfl(alpha, quad * 4 + 1);
        const float a2 = __shfl(alpha, quad * 4 + 2);
        const float a3 = __shfl(alpha, quad * 4 + 3);
#pragma unroll
        for (int nd = 0; nd < 8; nd++) {
          oacc[g][nd][0] *= a0; oacc[g][nd][1] *= a1; oacc[g][nd][2] *= a2; oacc[g][nd][3] *= a3;
        }
        l_i[g] *= alpha;
      }
      float s = 0.f;
#pragma unroll
      for (int mk = 0; mk < 4; mk++)
#pragma unroll
        for (int r = 0; r < 4; r++) {
          const float p = __builtin_amdgcn_exp2f(sacc[g][mk][r] - m_i[g]);
          sacc[g][mk][r] = p;
          s += p;
        }
      s += __shfl_xor(s, 16);
      s += __shfl_xor(s, 32);
      l_i[g] += s;
    }

    // P -> per-wave swizzled LDS via v_cvt_pk_bf16_f32 (1 op per 2 vals)
#pragma unroll
    for (int g = 0; g < 2; g++)
#pragma unroll
      for (int mk = 0; mk < 4; mk++) {
        const int subp = (4 * mk + quad) ^ (sw << 1);
        uint2 pk;
        pk.x = cvt_pk_bf16(sacc[g][mk][0], sacc[g][mk][1]);
        pk.y = cvt_pk_bf16(sacc[g][mk][2], sacc[g][mk][3]);
        *(uint2*)&Ps[wave][(g * 16 + row16) * 64 + subp * 4] = pk;
      }
    const int pc0 = quad ^ sw, pc1 = (4 + quad) ^ sw;
    short8 pf[2][2];
#pragma unroll
    for (int g = 0; g < 2; g++) {
      pf[g][0] = *(const short8*)&Ps[wave][(g * 16 + row16) * 64 + pc0 * 8];
      pf[g][1] = *(const short8*)&Ps[wave][(g * 16 + row16) * 64 + pc1 * 8];
    }
    // PV: V fragment loaded once, used for both q-halves
#pragma unroll
    for (int nd = 0; nd < 8; nd++) {
      const short8 vf0 = *(const short8*)&Vs[(nd * 16 + row16) * 64 + pc0 * 8];
      const short8 vf1 = *(const short8*)&Vs[(nd * 16 + row16) * 64 + pc1 * 8];
      oacc[0][nd] = __builtin_amdgcn_mfma_f32_16x16x32_bf16(pf[0][0], vf0, oacc[0][nd], 0, 0, 0);
      oacc[0][nd] = __builtin_amdgcn_mfma_f32_16x16x32_bf16(pf[0][1], vf1, oacc[0][nd], 0, 0, 0);
      oacc[1][nd] = __builtin_amdgcn_mfma_f32_16x16x32_bf16(pf[1][0], vf0, oacc[1][nd], 0, 0, 0);
      oacc[1][nd] = __builtin_amdgcn_mfma_f32_16x16x32_bf16(pf[1][1], vf1, oacc[1][nd], 0, 0, 0);
    }
  }
#pragma unroll
  for (int g = 0; g < 2; g++) {
    const size_t base = (size_t)(split * 12 + h) * 2304 + q0 + wave * 32 + g * 16;
#pragma unroll
    for (int nd = 0; nd < 8; nd++)
#pragma unroll
      for (int r = 0; r < 4; r++)
        Opart[(base + quad * 4 + r) * 128 + nd * 16 + row16] = f2bf(oacc[g][nd][r]);
    if (lane < 16) { Mp[base + lane] = m_i[g]; Lp[base + lane] = l_i[g]; }
  }
}

// ---------------- combine 3 splits (bf16 partials) -> attnout bf16 (S, 1536) ----------------
__global__ __launch_bounds__(256) void attn_combine(const u16* __restrict__ Opart,
                                                    const float* __restrict__ Mp,
                                                    const float* __restrict__ Lp,
                                                    u16* __restrict__ attnout) {
  const int idx = blockIdx.x * 256 + threadIdx.x;   // one per 4 output elems
  const int dd = (idx & 31) * 4;
  const int hq = idx >> 5;
  const int h = hq % 12, q = hq / 12;
  size_t b[3]; float ms[3], ls[3];
  float m = -1e30f;
#pragma unroll
  for (int s = 0; s < 3; s++) {
    b[s] = (size_t)(s * 12 + h) * 2304 + q;
    ms[s] = Mp[b[s]]; ls[s] = Lp[b[s]];
    m = fmaxf(m, ms[s]);
  }
  float w[3], denom = 0.f;
#pragma unroll
  for (int s = 0; s < 3; s++) { w[s] = exp2f(ms[s] - m); denom += ls[s] * w[s]; }
  const float inv = 1.0f / denom;
  float ox = 0.f, oy = 0.f, oz = 0.f, ow = 0.f;
#pragma unroll
  for (int s = 0; s < 3; s++) {
    const short4v o = *(const short4v*)&Opart[b[s] * 128 + dd];
    ox += bf2f((u16)o[0]) * w[s]; oy += bf2f((u16)o[1]) * w[s];
    oz += bf2f((u16)o[2]) * w[s]; ow += bf2f((u16)o[3]) * w[s];
  }
  short4v out;
  out[0] = (short)f2bf(ox * inv);
  out[1] = (short)f2bf(oy * inv);
  out[2] = (short)f2bf(oz * inv);
  out[3] = (short)f2bf(ow * inv);
  *(short4v*)&attnout[(size_t)idx * 4] = out;
}

// ---------------- launch ----------------
extern "C" void kernel_launch(void* const* d_in, const int* in_sizes, int n_in,
                              void* d_out, int out_size, void* d_ws, size_t ws_size,
                              hipStream_t stream) {
  const float* x        = (const float*)d_in[0];
  const float* y        = (const float*)d_in[1];
  const float* scale_x  = (const float*)d_in[2];
  const float* scale_y  = (const float*)d_in[3];
  const float* rope_cos = (const float*)d_in[4];
  const float* rope_sin = (const float*)d_in[5];
  const float* Wqkv_x   = (const float*)d_in[6];
  const float* bqkv_x   = (const float*)d_in[7];
  const float* Wqkv_y   = (const float*)d_in[8];
  const float* bqkv_y   = (const float*)d_in[9];
  const float* qnwx     = (const float*)d_in[10];
  const float* knwx     = (const float*)d_in[11];
  const float* qnwy     = (const float*)d_in[12];
  const float* knwy     = (const float*)d_in[13];
  const float* Wproj_x  = (const float*)d_in[14];
  const float* bproj_x  = (const float*)d_in[15];
  const float* Wproj_y  = (const float*)d_in[16];
  const float* bproj_y  = (const float*)d_in[17];
  float* out = (float*)d_out;

  char* ws = (char*)d_ws;
  size_t off = 0;
  auto take = [&](size_t bytes) { char* p = ws + off; off += (bytes + 255) & ~(size_t)255; return p; };
  u16* WqkvxT  = (u16*)take((size_t)4608 * 1536 * 2);
  u16* WqkvyT  = (u16*)take((size_t)4608 * 768 * 2);
  u16* WprojxT = (u16*)take((size_t)1536 * 1536 * 2);
  u16* WprojyT = (u16*)take((size_t)768 * 1536 * 2);
  u16* xm      = (u16*)take((size_t)2048 * 1536 * 2);
  u16* ym      = (u16*)take((size_t)256 * 768 * 2);
  u16* qkvx    = (u16*)take((size_t)2048 * 4608 * 2);
  u16* qkvy    = (u16*)take((size_t)256 * 4608 * 2);
  u16* Qb      = (u16*)take((size_t)12 * 2304 * 128 * 2);
  u16* Kb      = (u16*)take((size_t)12 * 2304 * 128 * 2);
  u16* Vt      = (u16*)take((size_t)12 * 128 * 2304 * 2);
  u16* attnout = (u16*)take((size_t)2304 * 1536 * 2);
  u16* Opart   = (u16*)take((size_t)3 * 12 * 2304 * 128 * 2);
  float* Mp    = (float*)take((size_t)3 * 12 * 2304 * 4);
  float* Lp    = (float*)take((size_t)3 * 12 * 2304 * 4);

  prep<<<dim3(144, 48, 5), dim3(32, 8), 0, stream>>>(Wqkv_x, WqkvxT, Wqkv_y, WqkvyT,
                                                     Wproj_x, WprojxT, Wproj_y, WprojyT,
                                                     x, scale_x, y, scale_y, xm, ym);

  gemm2<true><<<dim3(576, 1, 2), 256, 0, stream>>>(xm, WqkvxT, bqkv_x, qkvx, 2048, 4608, 1536,
                                                   ym, WqkvyT, bqkv_y, qkvy, 256, 4608, 768);

  qkv_post<<<dim3(72, 12), 256, 0, stream>>>(qkvx, qkvy, qnwx, knwx, qnwy, knwy,
                                             rope_cos, rope_sin, Qb, Kb, Vt);

  attn<<<dim3(720), 256, 0, stream>>>(Qb, Kb, Vt, Opart, Mp, Lp);
  attn_combine<<<(2304 * 1536 / 4) / 256, 256, 0, stream>>>(Opart, Mp, Lp, attnout);

  gemm2<false><<<dim3(192, 1, 2), 256, 0, stream>>>(attnout, WprojxT, bproj_x, out, 2048, 1536, 1536,
                                                    attnout + (size_t)2048 * 1536, WprojyT, bproj_y,
                                                    out + (size_t)2048 * 1536, 256, 768, 1536);
  (void)in_sizes; (void)n_in; (void)out_size; (void)ws_size;
}

// Round 10
// 294.499 us; speedup vs baseline: 1.1193x; 1.0140x over previous
//
#include <hip/hip_runtime.h>

typedef unsigned short u16;
typedef __attribute__((ext_vector_type(8))) short short8;
typedef __attribute__((ext_vector_type(4))) short short4v;
typedef __attribute__((ext_vector_type(4))) float floatx4;

// round-half-up bf16 (1 add + 1 shr); max error 0.5 ulp like RTNE (ties round up)
__device__ __forceinline__ u16 f2bf(float f) {
  return (u16)((__float_as_uint(f) + 0x8000u) >> 16);
}
__device__ __forceinline__ float bf2f(u16 v) {
  return __uint_as_float(((unsigned)v) << 16);
}
// pack two floats -> u32 of 2 bf16 (lo = a, hi = b) in ONE VALU op
__device__ __forceinline__ unsigned cvt_pk_bf16(float a, float b) {
  unsigned r;
  asm("v_cvt_pk_bf16_f32 %0, %1, %2" : "=v"(r) : "v"(a), "v"(b));
  return r;
}

#define GLD16(g, l) __builtin_amdgcn_global_load_lds( \
    (const __attribute__((address_space(1))) void*)(g), \
    (__attribute__((address_space(3))) void*)(l), 16, 0, 0)

// ---------------- prep: 4 weight transposes + rmsnorm(x,y), one launch ----------------
// z<4: transpose fp32(K,N)->bf16(N,K).  z==4: RMSNorm*(1+scale)->bf16 rows.
__global__ __launch_bounds__(256) void prep(const float* __restrict__ W0, u16* __restrict__ T0,
                                            const float* __restrict__ W1, u16* __restrict__ T1,
                                            const float* __restrict__ W2, u16* __restrict__ T2,
                                            const float* __restrict__ W3, u16* __restrict__ T3,
                                            const float* __restrict__ x, const float* __restrict__ scale_x,
                                            const float* __restrict__ y, const float* __restrict__ scale_y,
                                            u16* __restrict__ xm, u16* __restrict__ ym) {
  __shared__ float t[32][33];
  const int z = blockIdx.z;
  if (z < 4) {
    const float* in; u16* out; int K, N;
    switch (z) {
      case 0: in = W0; out = T0; K = 1536; N = 4608; break;
      case 1: in = W1; out = T1; K = 768;  N = 4608; break;
      case 2: in = W2; out = T2; K = 1536; N = 1536; break;
      default: in = W3; out = T3; K = 1536; N = 768; break;
    }
    const int n0 = blockIdx.x * 32, k0 = blockIdx.y * 32;
    if (n0 >= N || k0 >= K) return;
    const int tx = threadIdx.x, ty = threadIdx.y;   // 32 x 8
#pragma unroll
    for (int i = 0; i < 32; i += 8)
      t[ty + i][tx] = in[(size_t)(k0 + ty + i) * N + n0 + tx];
    __syncthreads();
#pragma unroll
    for (int i = 0; i < 32; i += 8)
      out[(size_t)(n0 + ty + i) * K + k0 + tx] = f2bf(t[tx][ty + i]);
  } else {
    const int row = blockIdx.y * 144 + blockIdx.x;
    if (row >= 2304) return;
    const int tid = threadIdx.y * 32 + threadIdx.x;
    const float* xr; const float* sc; u16* dst; int D;
    if (row < 2048) { D = 1536; xr = x + (size_t)row * D; sc = scale_x; dst = xm + (size_t)row * D; }
    else { D = 768; xr = y + (size_t)(row - 2048) * D; sc = scale_y; dst = ym + (size_t)(row - 2048) * D; }
    float ss = 0.f;
    for (int c = tid; c < D; c += 256) { float v = xr[c]; ss += v * v; }
    for (int off = 32; off > 0; off >>= 1) ss += __shfl_down(ss, off);
    __shared__ float red[4];
    if ((tid & 63) == 0) red[tid >> 6] = ss;
    __syncthreads();
    const float tot = red[0] + red[1] + red[2] + red[3];
    const float r = rsqrtf(tot / (float)D + 1e-6f);
    for (int c = tid; c < D; c += 256)
      dst[c] = f2bf(xr[c] * r * (1.0f + sc[c]));
  }
}

// ---------------- dual bf16 MFMA GEMM, 3-stage counted-vmcnt pipe + XCD n-stripe swizzle ----
// C(MxN) = A(MxK) * BT(NxK)^T + bias. M%128==0, N%128==0, K%32==0. (qkv path)
template <bool BOUT>
__global__ __launch_bounds__(256) void gemm2(const u16* __restrict__ A0, const u16* __restrict__ BT0,
                                             const float* __restrict__ bias0, void* __restrict__ C0,
                                             int M0, int N0, int K0,
                                             const u16* __restrict__ A1, const u16* __restrict__ BT1,
                                             const float* __restrict__ bias1, void* __restrict__ C1,
                                             int M1, int N1, int K1) {
  const u16 *A, *BT; const float* bias; void* Cout; int M, N, K;
  if (blockIdx.z == 0) { A = A0; BT = BT0; bias = bias0; Cout = C0; M = M0; N = N0; K = K0; }
  else { A = A1; BT = BT1; bias = bias1; Cout = C1; M = M1; N = N1; K = K1; }
  const int nty = M >> 7, ntx = N >> 7;
  const int W = ntx * nty;
  const int bid = blockIdx.x;
  const int xcd = bid & 7, local = bid >> 3;
  const int q = W >> 3, r = W & 7;
  const int cap = (xcd < r) ? q + 1 : q;
  if (local >= cap) return;
  const int w = (xcd < r) ? xcd * (q + 1) + local
                          : r * (q + 1) + (xcd - r) * q + local;
  const int tx = w / nty, ty = w - tx * nty;   // n-major: XCD's n-stripe, m-sweep inner
  const int bm = ty * 128, bn = tx * 128;

  __shared__ __align__(16) u16 As[3][128 * 32];
  __shared__ __align__(16) u16 Bs[3][128 * 32];
  const int tid = threadIdx.x;
  const int lane = tid & 63, wave = tid >> 6;
  const int wm = (wave & 1) * 64, wn = (wave >> 1) * 64;
  const int row16 = lane & 15, quad = lane >> 4;

  floatx4 acc[4][4] = {};
  const int r0 = lane >> 2, c4 = (lane & 3) * 8;
  const u16* Ag0 = A + (size_t)(bm + wave * 16 + r0) * K + c4;
  const u16* Ag1 = A + (size_t)(bm + (wave + 4) * 16 + r0) * K + c4;
  const u16* Bg0 = BT + (size_t)(bn + wave * 16 + r0) * K + c4;
  const u16* Bg1 = BT + (size_t)(bn + (wave + 4) * 16 + r0) * K + c4;
  const int d0 = wave * 512, d1 = (wave + 4) * 512;

  // prologue: stage tiles 0 and 1 (K >= 768 always here)
  GLD16(Ag0, &As[0][d0]);
  GLD16(Ag1, &As[0][d1]);
  GLD16(Bg0, &Bs[0][d0]);
  GLD16(Bg1, &Bs[0][d1]);
  GLD16(Ag0 + 32, &As[1][d0]);
  GLD16(Ag1 + 32, &As[1][d1]);
  GLD16(Bg0 + 32, &Bs[1][d0]);
  GLD16(Bg1 + 32, &Bs[1][d1]);

  int cur = 0;
  for (int k0 = 0; k0 < K; k0 += 32) {
    if (k0 + 64 < K) {
      int nxt2 = cur + 2; if (nxt2 >= 3) nxt2 -= 3;
      GLD16(Ag0 + k0 + 64, &As[nxt2][d0]);
      GLD16(Ag1 + k0 + 64, &As[nxt2][d1]);
      GLD16(Bg0 + k0 + 64, &Bs[nxt2][d0]);
      GLD16(Bg1 + k0 + 64, &Bs[nxt2][d1]);
      asm volatile("s_waitcnt vmcnt(8)" ::: "memory");  // tile t done; t+1,t+2 in flight
    } else if (k0 + 32 < K) {
      asm volatile("s_waitcnt vmcnt(4)" ::: "memory");  // tile t done; t+1 in flight
    } else {
      asm volatile("s_waitcnt vmcnt(0)" ::: "memory");  // last tile: drain
    }
    __builtin_amdgcn_s_barrier();
    asm volatile("" ::: "memory");
    short8 af[4], bf[4];
#pragma unroll
    for (int i = 0; i < 4; i++) {
      af[i] = *(const short8*)&As[cur][(wm + i * 16 + row16) * 32 + quad * 8];
      bf[i] = *(const short8*)&Bs[cur][(wn + i * 16 + row16) * 32 + quad * 8];
    }
#pragma unroll
    for (int mi = 0; mi < 4; mi++)
#pragma unroll
      for (int ni = 0; ni < 4; ni++)
        acc[mi][ni] = __builtin_amdgcn_mfma_f32_16x16x32_bf16(af[mi], bf[ni], acc[mi][ni], 0, 0, 0);
    asm volatile("" ::: "memory");
    __builtin_amdgcn_s_barrier();   // all waves done reading buf[cur]; next iter may overwrite it
    cur += 1; if (cur >= 3) cur -= 3;
  }
#pragma unroll
  for (int mi = 0; mi < 4; mi++) {
#pragma unroll
    for (int ni = 0; ni < 4; ni++) {
      const int col = bn + wn + ni * 16 + row16;
      const float b = bias[col];
      const int row0 = bm + wm + mi * 16 + quad * 4;
#pragma unroll
      for (int r2 = 0; r2 < 4; r2++) {
        const float v = acc[mi][ni][r2] + b;
        if constexpr (BOUT)
          ((u16*)Cout)[(size_t)(row0 + r2) * N + col] = f2bf(v);
        else
          ((float*)Cout)[(size_t)(row0 + r2) * N + col] = v;
      }
    }
  }
}

// ---------------- split-K x3 GEMM for proj: fp32 partials, no bias ----------------
// Proj's natural grid is 192+12 blocks = 0.75/CU — a quarter of the machine idle, nothing
// to hide barrier drains. 3 K-splits of 512 -> 612 working blocks (2.4/CU).
// Partials are deterministic fp32; proj_merge adds them + bias. Partial buffers ALIAS
// dead workspace regions (xm..Vt and WqkvxT) — total footprint unchanged from R8
// (R9's +53MB take() likely overran ws_size -> container fault).
__global__ __launch_bounds__(256) void gemm_splitk(const u16* __restrict__ A0, const u16* __restrict__ BT0,
                                                   float* __restrict__ C0, int M0, int N0, int K0,
                                                   const u16* __restrict__ A1, const u16* __restrict__ BT1,
                                                   float* __restrict__ C1, int M1, int N1, int K1) {
  const u16 *A, *BT; float* Cp; int M, N, K;
  if (blockIdx.z == 0) { A = A0; BT = BT0; Cp = C0; M = M0; N = N0; K = K0; }
  else { A = A1; BT = BT1; Cp = C1; M = M1; N = N1; K = K1; }
  const int nty = M >> 7, ntx = N >> 7;
  const int W = ntx * nty;
  const int split = blockIdx.x % 3, w = blockIdx.x / 3;
  if (w >= W) return;
  const int tx = w / nty, ty = w - tx * nty;
  const int bm = ty * 128, bn = tx * 128;
  const int Ks = K / 3;                     // 512: 16 K-tiles per split
  Cp += (size_t)split * M * N;

  __shared__ __align__(16) u16 As[3][128 * 32];
  __shared__ __align__(16) u16 Bs[3][128 * 32];
  const int tid = threadIdx.x;
  const int lane = tid & 63, wave = tid >> 6;
  const int wm = (wave & 1) * 64, wn = (wave >> 1) * 64;
  const int row16 = lane & 15, quad = lane >> 4;

  floatx4 acc[4][4] = {};
  const int r0 = lane >> 2, c4 = (lane & 3) * 8 + split * Ks;   // column base inside this split
  const u16* Ag0 = A + (size_t)(bm + wave * 16 + r0) * K + c4;
  const u16* Ag1 = A + (size_t)(bm + (wave + 4) * 16 + r0) * K + c4;
  const u16* Bg0 = BT + (size_t)(bn + wave * 16 + r0) * K + c4;
  const u16* Bg1 = BT + (size_t)(bn + (wave + 4) * 16 + r0) * K + c4;
  const int d0 = wave * 512, d1 = (wave + 4) * 512;

  GLD16(Ag0, &As[0][d0]);
  GLD16(Ag1, &As[0][d1]);
  GLD16(Bg0, &Bs[0][d0]);
  GLD16(Bg1, &Bs[0][d1]);
  GLD16(Ag0 + 32, &As[1][d0]);
  GLD16(Ag1 + 32, &As[1][d1]);
  GLD16(Bg0 + 32, &Bs[1][d0]);
  GLD16(Bg1 + 32, &Bs[1][d1]);

  int cur = 0;
  for (int k0 = 0; k0 < Ks; k0 += 32) {
    if (k0 + 64 < Ks) {
      int nxt2 = cur + 2; if (nxt2 >= 3) nxt2 -= 3;
      GLD16(Ag0 + k0 + 64, &As[nxt2][d0]);
      GLD16(Ag1 + k0 + 64, &As[nxt2][d1]);
      GLD16(Bg0 + k0 + 64, &Bs[nxt2][d0]);
      GLD16(Bg1 + k0 + 64, &Bs[nxt2][d1]);
      asm volatile("s_waitcnt vmcnt(8)" ::: "memory");
    } else if (k0 + 32 < Ks) {
      asm volatile("s_waitcnt vmcnt(4)" ::: "memory");
    } else {
      asm volatile("s_waitcnt vmcnt(0)" ::: "memory");
    }
    __builtin_amdgcn_s_barrier();
    asm volatile("" ::: "memory");
    short8 af[4], bf[4];
#pragma unroll
    for (int i = 0; i < 4; i++) {
      af[i] = *(const short8*)&As[cur][(wm + i * 16 + row16) * 32 + quad * 8];
      bf[i] = *(const short8*)&Bs[cur][(wn + i * 16 + row16) * 32 + quad * 8];
    }
#pragma unroll
    for (int mi = 0; mi < 4; mi++)
#pragma unroll
      for (int ni = 0; ni < 4; ni++)
        acc[mi][ni] = __builtin_amdgcn_mfma_f32_16x16x32_bf16(af[mi], bf[ni], acc[mi][ni], 0, 0, 0);
    asm volatile("" ::: "memory");
    __builtin_amdgcn_s_barrier();
    cur += 1; if (cur >= 3) cur -= 3;
  }
#pragma unroll
  for (int mi = 0; mi < 4; mi++) {
#pragma unroll
    for (int ni = 0; ni < 4; ni++) {
      const int col = bn + wn + ni * 16 + row16;
      const int row0 = bm + wm + mi * 16 + quad * 4;
#pragma unroll
      for (int r2 = 0; r2 < 4; r2++)
        Cp[(size_t)(row0 + r2) * N + col] = acc[mi][ni][r2];
    }
  }
}

// ---------------- proj merge: out = sum(3 partials) + bias ----------------
__global__ __launch_bounds__(256) void proj_merge(const float* __restrict__ Px,
                                                  const float* __restrict__ Py,
                                                  const float* __restrict__ bx,
                                                  const float* __restrict__ by,
                                                  float* __restrict__ out) {
  const int z = blockIdx.z;
  const float* P; const float* bias; float* o; int N; size_t total;
  if (z == 0) { P = Px; bias = bx; o = out; N = 1536; total = (size_t)2048 * 1536; }
  else { P = Py; bias = by; o = out + (size_t)2048 * 1536; N = 768; total = (size_t)256 * 768; }
  const size_t idx4 = ((size_t)blockIdx.x * 256 + threadIdx.x) * 4;
  if (idx4 >= total) return;
  const int col = (int)(idx4 % (size_t)N);
  const float4 p0 = *(const float4*)&P[idx4];
  const float4 p1 = *(const float4*)&P[total + idx4];
  const float4 p2 = *(const float4*)&P[2 * total + idx4];
  const float4 bv = *(const float4*)&bias[col];
  float4 r;
  r.x = p0.x + p1.x + p2.x + bv.x;
  r.y = p0.y + p1.y + p2.y + bv.y;
  r.z = p0.z + p1.z + p2.z + bv.z;
  r.w = p0.w + p1.w + p2.w + bv.w;
  *(float4*)&o[idx4] = r;
}

// ---------------- per-head q/k RMSNorm + RoPE(x only) + V transpose fused ----------------
// Block = 32 seq x 1 head, 256 threads. RoPE pairs in-lane; V LDS-transposed to Vt (h,d,s).
// Q folded with (1/sqrt(D)) * log2(e) so attention works in exp2 domain.
__global__ __launch_bounds__(256) void qkv_post(const u16* __restrict__ qkvx,
                                                const u16* __restrict__ qkvy,
                                                const float* __restrict__ qnwx, const float* __restrict__ knwx,
                                                const float* __restrict__ qnwy, const float* __restrict__ knwy,
                                                const float* __restrict__ rcos, const float* __restrict__ rsin,
                                                u16* __restrict__ Q, u16* __restrict__ Kb, u16* __restrict__ Vt) {
  const int s0 = blockIdx.x * 32, h = blockIdx.y;
  const int tid = threadIdx.x, wave = tid >> 6, lane = tid & 63;
  const int sl = wave * 8 + (lane >> 3);     // local seq 0..31
  const int s = s0 + sl;
  const int d0 = (lane & 7) * 16;
  const bool isx = s < 2048;
  const u16* base = isx ? (qkvx + (size_t)s * 4608) : (qkvy + (size_t)(s - 2048) * 4608);

  const short8 qv0 = *(const short8*)(base + h * 128 + d0);
  const short8 qv1 = *(const short8*)(base + h * 128 + d0 + 8);
  const short8 kv0 = *(const short8*)(base + 1536 + h * 128 + d0);
  const short8 kv1 = *(const short8*)(base + 1536 + h * 128 + d0 + 8);
  const short8 vv0 = *(const short8*)(base + 3072 + h * 128 + d0);
  const short8 vv1 = *(const short8*)(base + 3072 + h * 128 + d0 + 8);

  float q[16], k[16];
#pragma unroll
  for (int j = 0; j < 8; j++) {
    q[j] = bf2f((u16)qv0[j]); q[j + 8] = bf2f((u16)qv1[j]);
    k[j] = bf2f((u16)kv0[j]); k[j + 8] = bf2f((u16)kv1[j]);
  }
  float sq = 0.f, sk = 0.f;
#pragma unroll
  for (int j = 0; j < 16; j++) { sq += q[j] * q[j]; sk += k[j] * k[j]; }
#pragma unroll
  for (int off = 1; off <= 4; off <<= 1) { sq += __shfl_xor(sq, off); sk += __shfl_xor(sk, off); }
  const float rq = rsqrtf(sq * (1.f / 128.f) + 1e-5f);
  const float rk = rsqrtf(sk * (1.f / 128.f) + 1e-5f);

  const float* qw = isx ? qnwx : qnwy;
  const float* kw = isx ? knwx : knwy;
#pragma unroll
  for (int j = 0; j < 16; j++) {
    q[j] = q[j] * rq * qw[d0 + j];
    k[j] = k[j] * rk * kw[d0 + j];
  }
  if (isx) {
    const float* cb = rcos + ((size_t)s * 12 + h) * 64 + (d0 >> 1);
    const float* sb = rsin + ((size_t)s * 12 + h) * 64 + (d0 >> 1);
#pragma unroll
    for (int p = 0; p < 8; p++) {
      const float c = cb[p], sn = sb[p];
      const float qe = q[2 * p], qo = q[2 * p + 1];
      const float ke = k[2 * p], ko = k[2 * p + 1];
      q[2 * p] = qe * c - qo * sn; q[2 * p + 1] = qe * sn + qo * c;
      k[2 * p] = ke * c - ko * sn; k[2 * p + 1] = ke * sn + ko * c;
    }
  }
  u16 qo16[16], ko16[16];
#pragma unroll
  for (int j = 0; j < 16; j++) {
    qo16[j] = f2bf(q[j] * 0.12751737942f);  // (1/sqrt(128)) * log2(e)
    ko16[j] = f2bf(k[j]);
  }
  const size_t o = ((size_t)h * 2304 + s) * 128 + d0;
  *(short8*)(Q + o) = *(const short8*)&qo16[0];
  *(short8*)(Q + o + 8) = *(const short8*)&qo16[8];
  *(short8*)(Kb + o) = *(const short8*)&ko16[0];
  *(short8*)(Kb + o + 8) = *(const short8*)&ko16[8];

  // V transpose: (32 s x 128 d) block -> Vt (h, d, s)
  __shared__ u16 vlds[128][33];
#pragma unroll
  for (int j = 0; j < 8; j++) {
    vlds[d0 + j][sl] = (u16)vv0[j];
    vlds[d0 + 8 + j][sl] = (u16)vv1[j];
  }
  __syncthreads();
  const int row = tid >> 1, sc = (tid & 1) * 16;
  u16 tmp[16];
#pragma unroll
  for (int j = 0; j < 16; j++) tmp[j] = vlds[row][sc + j];
  u16* vdst = Vt + ((size_t)h * 128 + row) * 2304 + s0 + sc;
  *(short8*)vdst = *(const short8*)&tmp[0];
  *(short8*)(vdst + 8) = *(const short8*)&tmp[8];
}

// ---------------- flash attention: 32 q/wave, 128 q/block, 3-way split-K (R6-exact) -------
// GLD16-staged K AND V (R7 showed direct-L2 V costs +29us: per-wave load latency on the
// PV critical path + 4x V traffic). 48KB LDS, 3 blocks/CU, all 648 working blocks resident.
__global__ __launch_bounds__(256, 3) void attn(const u16* __restrict__ Q, const u16* __restrict__ Kb,
                                               const u16* __restrict__ Vt,
                                               u16* __restrict__ Opart,
                                               float* __restrict__ Mp, float* __restrict__ Lp) {
  const int bid = blockIdx.x;
  const int xcd = bid & 7, local = bid >> 3;     // 0..89
  const int slot = local / 18, qt = local % 18;
  const int combo = slot * 8 + xcd;              // 0..39
  if (combo >= 36) return;                       // 72 pad blocks exit
  const int h = combo % 12, split = combo / 12;  // split 0..2
  const int q0 = qt * 128;
  const int tid = threadIdx.x, lane = tid & 63, wave = tid >> 6;
  const int row16 = lane & 15, quad = lane >> 4;
  const u16* Qh = Q + (size_t)h * 2304 * 128;
  const u16* Kh = Kb + (size_t)h * 2304 * 128;
  const u16* Vh = Vt + (size_t)h * 128 * 2304;

  __shared__ __align__(16) u16 Ks[64 * 128];    // swizzled: 64 key-rows x 16 chunks
  __shared__ __align__(16) u16 Vs[128 * 64];    // swizzled: 128 d-rows x 8 chunks
  __shared__ __align__(16) u16 Ps[4][32 * 64];  // per-wave P (32 q x 64 keys), swizzled

  short8 qf[2][4];
#pragma unroll
  for (int g = 0; g < 2; g++) {
    const u16* qrow = Qh + (size_t)(q0 + wave * 32 + g * 16 + row16) * 128;
#pragma unroll
    for (int kk = 0; kk < 4; kk++) qf[g][kk] = *(const short8*)(qrow + kk * 32 + quad * 8);
  }
  floatx4 oacc[2][8] = {};
  float m_i[2] = {-1e30f, -1e30f}, l_i[2] = {0.f, 0.f};

  const u16* Kp[4]; const u16* Vp[4];
#pragma unroll
  for (int i = 0; i < 4; i++) {
    const int j = i * 4 + wave;
    const int krow = j * 4 + (lane >> 4);        // key row 0..63
    const int kcol = ((lane & 15) ^ (krow & 7)) * 8;
    const int vrow = j * 8 + (lane >> 3);        // d row 0..127
    const int vcol = ((lane & 7) ^ (vrow & 7)) * 8;
    Kp[i] = Kh + (size_t)krow * 128 + kcol;
    Vp[i] = Vh + (size_t)vrow * 2304 + vcol;
  }
  const int sw = row16 & 7;
  const int kbeg = split * 768, kend = kbeg + 768;

  for (int kt = kbeg; kt < kend; kt += 64) {
    __syncthreads();
#pragma unroll
    for (int i = 0; i < 4; i++) {
      GLD16(Kp[i] + (size_t)kt * 128, Ks + (i * 4 + wave) * 512);
      GLD16(Vp[i] + kt, Vs + (i * 4 + wave) * 512);
    }
    __syncthreads();

    // S^T for both q-halves; K fragment loaded once, used twice
    floatx4 sacc[2][4] = {};
#pragma unroll
    for (int mk = 0; mk < 4; mk++) {
#pragma unroll
      for (int kk = 0; kk < 4; kk++) {
        const int c = (4 * kk + quad) ^ sw;
        const short8 kfrag = *(const short8*)&Ks[(mk * 16 + row16) * 128 + c * 8];
        sacc[0][mk] = __builtin_amdgcn_mfma_f32_16x16x32_bf16(kfrag, qf[0][kk], sacc[0][mk], 0, 0, 0);
        sacc[1][mk] = __builtin_amdgcn_mfma_f32_16x16x32_bf16(kfrag, qf[1][kk], sacc[1][mk], 0, 0, 0);
      }
    }
    // online softmax per q-half: keys in-lane, q-col = row16
#pragma unroll
    for (int g = 0; g < 2; g++) {
      float mx = sacc[g][0][0];
#pragma unroll
      for (int mk = 0; mk < 4; mk++)
#pragma unroll
        for (int r = 0; r < 4; r++) mx = fmaxf(mx, sacc[g][mk][r]);
      mx = fmaxf(mx, __shfl_xor(mx, 16));
      mx = fmaxf(mx, __shfl_xor(mx, 32));
      if (__any(mx > m_i[g] + 8.f)) {  // defer-max: only rescale on >2^8 growth
        const float mnew = fmaxf(m_i[g], mx);
        const float alpha = __builtin_amdgcn_exp2f(m_i[g] - mnew);
        m_i[g] = mnew;
        const float a0 = __shfl(alpha, quad * 4 + 0);
        const float a1 = __shfl(alpha, quad * 4 + 1);
        const float a2 = __shfl(alpha, quad * 4 + 2);
        const float a3 = __shfl(alpha, quad * 4 + 3);
#pragma unroll
        for (int nd = 0; nd < 8; nd++) {
          oacc[g][nd][0] *= a0; oacc[g][nd][1] *= a1; oacc[g][nd][2] *= a2; oacc[g][nd][3] *= a3;
        }
        l_i[g] *= alpha;
      }
      float s = 0.f;
#pragma unroll
      for (int mk = 0; mk < 4; mk++)
#pragma unroll
        for (int r = 0; r < 4; r++) {
          const float p = __builtin_amdgcn_exp2f(sacc[g][mk][r] - m_i[g]);
          sacc[g][mk][r] = p;
          s += p;
        }
      s += __shfl_xor(s, 16);
      s += __shfl_xor(s, 32);
      l_i[g] += s;
    }

    // P -> per-wave swizzled LDS via v_cvt_pk_bf16_f32 (1 op per 2 vals)
#pragma unroll
    for (int g = 0; g < 2; g++)
#pragma unroll
      for (int mk = 0; mk < 4; mk++) {
        const int subp = (4 * mk + quad) ^ (sw << 1);
        uint2 pk;
        pk.x = cvt_pk_bf16(sacc[g][mk][0], sacc[g][mk][1]);
        pk.y = cvt_pk_bf16(sacc[g][mk][2], sacc[g][mk][3]);
        *(uint2*)&Ps[wave][(g * 16 + row16) * 64 + subp * 4] = pk;
      }
    const int pc0 = quad ^ sw, pc1 = (4 + quad) ^ sw;
    short8 pf[2][2];
#pragma unroll
    for (int g = 0; g < 2; g++) {
      pf[g][0] = *(const short8*)&Ps[wave][(g * 16 + row16) * 64 + pc0 * 8];
      pf[g][1] = *(const short8*)&Ps[wave][(g * 16 + row16) * 64 + pc1 * 8];
    }
    // PV: V fragment loaded once, used for both q-halves
#pragma unroll
    for (int nd = 0; nd < 8; nd++) {
      const short8 vf0 = *(const short8*)&Vs[(nd * 16 + row16) * 64 + pc0 * 8];
      const short8 vf1 = *(const short8*)&Vs[(nd * 16 + row16) * 64 + pc1 * 8];
      oacc[0][nd] = __builtin_amdgcn_mfma_f32_16x16x32_bf16(pf[0][0], vf0, oacc[0][nd], 0, 0, 0);
      oacc[0][nd] = __builtin_amdgcn_mfma_f32_16x16x32_bf16(pf[0][1], vf1, oacc[0][nd], 0, 0, 0);
      oacc[1][nd] = __builtin_amdgcn_mfma_f32_16x16x32_bf16(pf[1][0], vf0, oacc[1][nd], 0, 0, 0);
      oacc[1][nd] = __builtin_amdgcn_mfma_f32_16x16x32_bf16(pf[1][1], vf1, oacc[1][nd], 0, 0, 0);
    }
  }
#pragma unroll
  for (int g = 0; g < 2; g++) {
    const size_t base = (size_t)(split * 12 + h) * 2304 + q0 + wave * 32 + g * 16;
#pragma unroll
    for (int nd = 0; nd < 8; nd++)
#pragma unroll
      for (int r = 0; r < 4; r++)
        Opart[(base + quad * 4 + r) * 128 + nd * 16 + row16] = f2bf(oacc[g][nd][r]);
    if (lane < 16) { Mp[base + lane] = m_i[g]; Lp[base + lane] = l_i[g]; }
  }
}

// ---------------- combine 3 splits (bf16 partials) -> attnout bf16 (S, 1536) ----------------
__global__ __launch_bounds__(256) void attn_combine(const u16* __restrict__ Opart,
                                                    const float* __restrict__ Mp,
                                                    const float* __restrict__ Lp,
                                                    u16* __restrict__ attnout) {
  const int idx = blockIdx.x * 256 + threadIdx.x;   // one per 4 output elems
  const int dd = (idx & 31) * 4;
  const int hq = idx >> 5;
  const int h = hq % 12, q = hq / 12;
  size_t b[3]; float ms[3], ls[3];
  float m = -1e30f;
#pragma unroll
  for (int s = 0; s < 3; s++) {
    b[s] = (size_t)(s * 12 + h) * 2304 + q;
    ms[s] = Mp[b[s]]; ls[s] = Lp[b[s]];
    m = fmaxf(m, ms[s]);
  }
  float w[3], denom = 0.f;
#pragma unroll
  for (int s = 0; s < 3; s++) { w[s] = exp2f(ms[s] - m); denom += ls[s] * w[s]; }
  const float inv = 1.0f / denom;
  float ox = 0.f, oy = 0.f, oz = 0.f, ow = 0.f;
#pragma unroll
  for (int s = 0; s < 3; s++) {
    const short4v o = *(const short4v*)&Opart[b[s] * 128 + dd];
    ox += bf2f((u16)o[0]) * w[s]; oy += bf2f((u16)o[1]) * w[s];
    oz += bf2f((u16)o[2]) * w[s]; ow += bf2f((u16)o[3]) * w[s];
  }
  short4v out;
  out[0] = (short)f2bf(ox * inv);
  out[1] = (short)f2bf(oy * inv);
  out[2] = (short)f2bf(oz * inv);
  out[3] = (short)f2bf(ow * inv);
  *(short4v*)&attnout[(size_t)idx * 4] = out;
}

// ---------------- launch ----------------
extern "C" void kernel_launch(void* const* d_in, const int* in_sizes, int n_in,
                              void* d_out, int out_size, void* d_ws, size_t ws_size,
                              hipStream_t stream) {
  const float* x        = (const float*)d_in[0];
  const float* y        = (const float*)d_in[1];
  const float* scale_x  = (const float*)d_in[2];
  const float* scale_y  = (const float*)d_in[3];
  const float* rope_cos = (const float*)d_in[4];
  const float* rope_sin = (const float*)d_in[5];
  const float* Wqkv_x   = (const float*)d_in[6];
  const float* bqkv_x   = (const float*)d_in[7];
  const float* Wqkv_y   = (const float*)d_in[8];
  const float* bqkv_y   = (const float*)d_in[9];
  const float* qnwx     = (const float*)d_in[10];
  const float* knwx     = (const float*)d_in[11];
  const float* qnwy     = (const float*)d_in[12];
  const float* knwy     = (const float*)d_in[13];
  const float* Wproj_x  = (const float*)d_in[14];
  const float* bproj_x  = (const float*)d_in[15];
  const float* Wproj_y  = (const float*)d_in[16];
  const float* bproj_y  = (const float*)d_in[17];
  float* out = (float*)d_out;

  char* ws = (char*)d_ws;
  size_t off = 0;
  auto take = [&](size_t bytes) { char* p = ws + off; off += (bytes + 255) & ~(size_t)255; return p; };
  u16* WqkvxT  = (u16*)take((size_t)4608 * 1536 * 2);
  u16* WqkvyT  = (u16*)take((size_t)4608 * 768 * 2);
  u16* WprojxT = (u16*)take((size_t)1536 * 1536 * 2);
  u16* WprojyT = (u16*)take((size_t)768 * 1536 * 2);
  u16* xm      = (u16*)take((size_t)2048 * 1536 * 2);
  u16* ym      = (u16*)take((size_t)256 * 768 * 2);
  u16* qkvx    = (u16*)take((size_t)2048 * 4608 * 2);
  u16* qkvy    = (u16*)take((size_t)256 * 4608 * 2);
  u16* Qb      = (u16*)take((size_t)12 * 2304 * 128 * 2);
  u16* Kb      = (u16*)take((size_t)12 * 2304 * 128 * 2);
  u16* Vt      = (u16*)take((size_t)12 * 128 * 2304 * 2);
  u16* attnout = (u16*)take((size_t)2304 * 1536 * 2);
  u16* Opart   = (u16*)take((size_t)3 * 12 * 2304 * 128 * 2);
  float* Mp    = (float*)take((size_t)3 * 12 * 2304 * 4);
  float* Lp    = (float*)take((size_t)3 * 12 * 2304 * 4);
  // Split-K partials ALIAS dead regions (no new workspace; R8 footprint preserved):
  // Cpx (3 x 2048x1536 fp32 = 37.7MB) sits on xm..Vt (49.3MB, dead after attn).
  // Cpy (3 x 256x768 fp32 = 2.4MB) sits on WqkvxT (14.2MB, dead after qkv gemm).
  float* Cpx = (float*)xm;
  float* Cpy = (float*)WqkvxT;

  prep<<<dim3(144, 48, 5), dim3(32, 8), 0, stream>>>(Wqkv_x, WqkvxT, Wqkv_y, WqkvyT,
                                                     Wproj_x, WprojxT, Wproj_y, WprojyT,
                                                     x, scale_x, y, scale_y, xm, ym);

  gemm2<true><<<dim3(576, 1, 2), 256, 0, stream>>>(xm, WqkvxT, bqkv_x, qkvx, 2048, 4608, 1536,
                                                   ym, WqkvyT, bqkv_y, qkvy, 256, 4608, 768);

  qkv_post<<<dim3(72, 12), 256, 0, stream>>>(qkvx, qkvy, qnwx, knwx, qnwy, knwy,
                                             rope_cos, rope_sin, Qb, Kb, Vt);

  attn<<<dim3(720), 256, 0, stream>>>(Qb, Kb, Vt, Opart, Mp, Lp);
  attn_combine<<<(2304 * 1536 / 4) / 256, 256, 0, stream>>>(Opart, Mp, Lp, attnout);

  gemm_splitk<<<dim3(576, 1, 2), 256, 0, stream>>>(attnout, WprojxT, Cpx, 2048, 1536, 1536,
                                                   attnout + (size_t)2048 * 1536, WprojyT, Cpy,
                                                   256, 768, 1536);
  proj_merge<<<dim3(3072, 1, 2), 256, 0, stream>>>(Cpx, Cpy, bproj_x, bproj_y, out);
  (void)in_sizes; (void)n_in; (void)out_size; (void)ws_size;
}